// Round 1
// baseline (3300.358 us; speedup 1.0000x reference)
//
#include <hip/hip_runtime.h>
#include <math.h>

#define HW   1024
#define C_IN 768
#define B_N  8
#define TK   72      // K-tile: 8 channels x 9 taps
#define ASTR 68      // padded LDS stride for A tile (68 = 64+4, keeps 16B align, breaks bank conflicts)

// ---------------------------------------------------------------------------
// Kernel 1: offset/mask 3x3 convs (27 out channels over 768 in channels)
// one thread per (b, oc, pixel)
// ---------------------------------------------------------------------------
__global__ __launch_bounds__(256) void offmask_kernel(
    const float* __restrict__ x,
    const float* __restrict__ offw, const float* __restrict__ offb,
    const float* __restrict__ mskw, const float* __restrict__ mskb,
    float* __restrict__ offs, float* __restrict__ maskbuf)
{
    int t   = blockIdx.x * 256 + threadIdx.x;     // B*27*HW threads
    int hw  = t & 1023;
    int boc = t >> 10;
    int oc  = boc % 27;
    int b   = boc / 27;
    int h = hw >> 5, w = hw & 31;

    const float* wp = (oc < 18) ? (offw + (size_t)oc * (C_IN * 9))
                                : (mskw + (size_t)(oc - 18) * (C_IN * 9));
    float acc = (oc < 18) ? offb[oc] : mskb[oc - 18];

    int   toff[9];
    float tfl[9];
#pragma unroll
    for (int tap = 0; tap < 9; ++tap) {
        int ki = tap / 3, kj = tap % 3;
        int yy = h + ki - 1, xx = w + kj - 1;
        bool ok = (yy >= 0 && yy < 32 && xx >= 0 && xx < 32);
        toff[tap] = ok ? (yy * 32 + xx) : 0;
        tfl[tap]  = ok ? 1.0f : 0.0f;
    }

    const float* xb = x + (size_t)b * C_IN * HW;
    for (int c = 0; c < C_IN; ++c) {
        const float* xc = xb + c * HW;
        const float* wc = wp + c * 9;
#pragma unroll
        for (int tap = 0; tap < 9; ++tap) {
            acc += xc[toff[tap]] * tfl[tap] * wc[tap];
        }
    }

    if (oc < 18) {
        acc = fminf(fmaxf(acc, -8.0f), 8.0f);      // max_off = 32//4 = 8
        offs[((b * 18 + oc) << 10) + hw] = acc;
    } else {
        maskbuf[((b * 9 + (oc - 18)) << 10) + hw] = 2.0f / (1.0f + expf(-acc));
    }
}

// ---------------------------------------------------------------------------
// Kernel 2: deformable conv as fused-sampling GEMM.
// Block = 64 o-channels x 64 pixels, 256 threads (16x16), 4x4 micro-tile.
// ---------------------------------------------------------------------------
__global__ __launch_bounds__(256) void deform_gemm_kernel(
    const float* __restrict__ x, const float* __restrict__ pw,
    const float* __restrict__ pb,
    const float* __restrict__ offs, const float* __restrict__ maskbuf,
    float* __restrict__ y)
{
    __shared__ float4 meta_w[9 * 64];
    __shared__ int4   meta_i[9 * 64];
    __shared__ float  As[TK * ASTR];
    __shared__ float  Bs[TK * 64];

    const int b  = blockIdx.z;
    const int o0 = blockIdx.y * 64;
    const int p0 = blockIdx.x * 64;
    const int tid = threadIdx.x;
    const int tx = tid & 15, ty = tid >> 4;

    // ---- Phase A: bilinear sampling metadata for this pixel tile ----
    for (int idx = tid; idx < 9 * 64; idx += 256) {
        int j = idx & 63, k = idx >> 6;
        int hw = p0 + j;
        int h = hw >> 5, w = hw & 31;
        float dy = offs[((b * 18 + 2 * k) << 10) + hw];
        float dx = offs[((b * 18 + 2 * k + 1) << 10) + hw];
        float m  = maskbuf[((b * 9 + k) << 10) + hw];
        float ys = dy + (float)(h + k / 3 - 1);
        float xs = dx + (float)(w + k % 3 - 1);
        float fy = floorf(ys), fx = floorf(xs);
        float wy = ys - fy, wx = xs - fx;
        int iy0 = (int)fy, ix0 = (int)fx;
        int iy1 = iy0 + 1, ix1 = ix0 + 1;
        float vy0 = (iy0 >= 0 && iy0 < 32) ? 1.f : 0.f;
        float vy1 = (iy1 >= 0 && iy1 < 32) ? 1.f : 0.f;
        float vx0 = (ix0 >= 0 && ix0 < 32) ? 1.f : 0.f;
        float vx1 = (ix1 >= 0 && ix1 < 32) ? 1.f : 0.f;
        int cy0 = min(max(iy0, 0), 31), cx0 = min(max(ix0, 0), 31);
        int cy1 = min(max(iy1, 0), 31), cx1 = min(max(ix1, 0), 31);
        float4 wv;
        wv.x = (1.f - wy) * (1.f - wx) * m * vy0 * vx0;
        wv.y = (1.f - wy) * wx         * m * vy0 * vx1;
        wv.z = wy         * (1.f - wx) * m * vy1 * vx0;
        wv.w = wy         * wx         * m * vy1 * vx1;
        int4 iv;
        iv.x = cy0 * 32 + cx0; iv.y = cy0 * 32 + cx1;
        iv.z = cy1 * 32 + cx0; iv.w = cy1 * 32 + cx1;
        meta_w[idx] = wv; meta_i[idx] = iv;
    }
    __syncthreads();

    float acc[4][4] = {{0.f}};
    const float* xb = x + (size_t)b * C_IN * HW;

    for (int c0 = 0; c0 < C_IN; c0 += 8) {
        // stage A: proj weights [o][ck] -> LDS As[kkl][o] (transposed, padded)
        for (int idx = tid; idx < 64 * TK; idx += 256) {
            int o = idx / TK;
            int kkl = idx - o * TK;
            As[kkl * ASTR + o] = pw[(size_t)(o0 + o) * 6912 + c0 * 9 + kkl];
        }
        // stage B: gather-bilinear sampled[ck][pixel]
        for (int idx = tid; idx < TK * 64; idx += 256) {
            int kkl = idx >> 6, j = idx & 63;
            int cq = kkl / 9;
            int k  = kkl - cq * 9;
            const float* xp = xb + (c0 + cq) * HW;
            float4 wv = meta_w[(k << 6) + j];
            int4   iv = meta_i[(k << 6) + j];
            Bs[(kkl << 6) + j] = wv.x * xp[iv.x] + wv.y * xp[iv.y] +
                                 wv.z * xp[iv.z] + wv.w * xp[iv.w];
        }
        __syncthreads();

#pragma unroll 4
        for (int kkl = 0; kkl < TK; ++kkl) {
            float4 a4 = *(const float4*)&As[kkl * ASTR + ty * 4];
            float4 b4 = *(const float4*)&Bs[(kkl << 6) + tx * 4];
            acc[0][0] += a4.x * b4.x; acc[0][1] += a4.x * b4.y;
            acc[0][2] += a4.x * b4.z; acc[0][3] += a4.x * b4.w;
            acc[1][0] += a4.y * b4.x; acc[1][1] += a4.y * b4.y;
            acc[1][2] += a4.y * b4.z; acc[1][3] += a4.y * b4.w;
            acc[2][0] += a4.z * b4.x; acc[2][1] += a4.z * b4.y;
            acc[2][2] += a4.z * b4.z; acc[2][3] += a4.z * b4.w;
            acc[3][0] += a4.w * b4.x; acc[3][1] += a4.w * b4.y;
            acc[3][2] += a4.w * b4.z; acc[3][3] += a4.w * b4.w;
        }
        __syncthreads();
    }

#pragma unroll
    for (int i = 0; i < 4; ++i) {
        int o = o0 + ty * 4 + i;
        float bias = pb[o];
        float4 v;
        v.x = acc[i][0] + bias; v.y = acc[i][1] + bias;
        v.z = acc[i][2] + bias; v.w = acc[i][3] + bias;
        *(float4*)&y[(((size_t)b * 768 + o) << 10) + p0 + tx * 4] = v;
    }
}

// ---------------------------------------------------------------------------
// Kernel 3: per-channel mean / rstd over (B, H, W)
// ---------------------------------------------------------------------------
__global__ __launch_bounds__(256) void stats_kernel(
    const float* __restrict__ y, float* __restrict__ stats)
{
    int o = blockIdx.x;
    int tid = threadIdx.x;
    float s1 = 0.f, s2 = 0.f;
    for (int i = tid; i < B_N * HW; i += 256) {
        int b = i >> 10, hw = i & 1023;
        float v = y[(((size_t)b * 768 + o) << 10) + hw];
        s1 += v; s2 += v * v;
    }
#pragma unroll
    for (int off = 32; off > 0; off >>= 1) {
        s1 += __shfl_down(s1, off);
        s2 += __shfl_down(s2, off);
    }
    __shared__ float ls1[4], ls2[4];
    int wid = tid >> 6, lane = tid & 63;
    if (lane == 0) { ls1[wid] = s1; ls2[wid] = s2; }
    __syncthreads();
    if (tid == 0) {
        float t1 = ls1[0] + ls1[1] + ls1[2] + ls1[3];
        float t2 = ls2[0] + ls2[1] + ls2[2] + ls2[3];
        float mean = t1 * (1.0f / 8192.0f);
        float var  = t2 * (1.0f / 8192.0f) - mean * mean;
        stats[o]       = mean;
        stats[768 + o] = 1.0f / sqrtf(var + 1e-5f);
    }
}

// ---------------------------------------------------------------------------
// Kernel 4: normalize + exact GELU + residual, in-place on y (= d_out)
// ---------------------------------------------------------------------------
__global__ __launch_bounds__(256) void finalize_kernel(
    const float* __restrict__ x, const float* __restrict__ stats,
    const float* __restrict__ gamma, const float* __restrict__ beta,
    float* __restrict__ y)
{
    const int total4 = B_N * 768 * HW / 4;
    for (int f = blockIdx.x * 256 + threadIdx.x; f < total4;
         f += gridDim.x * 256) {
        int e = f << 2;
        int o = (e >> 10) % 768;
        float mean = stats[o], rstd = stats[768 + o];
        float ga = gamma[o], be = beta[o];
        float4 v  = ((const float4*)y)[f];
        float4 xv = ((const float4*)x)[f];
        float4 r;
        {
            float yn = (v.x - mean) * rstd * ga + be;
            r.x = xv.x + 0.5f * yn * (1.0f + erff(yn * 0.70710678118654752f));
        }
        {
            float yn = (v.y - mean) * rstd * ga + be;
            r.y = xv.y + 0.5f * yn * (1.0f + erff(yn * 0.70710678118654752f));
        }
        {
            float yn = (v.z - mean) * rstd * ga + be;
            r.z = xv.z + 0.5f * yn * (1.0f + erff(yn * 0.70710678118654752f));
        }
        {
            float yn = (v.w - mean) * rstd * ga + be;
            r.w = xv.w + 0.5f * yn * (1.0f + erff(yn * 0.70710678118654752f));
        }
        ((float4*)y)[f] = r;
    }
}

// ---------------------------------------------------------------------------
extern "C" void kernel_launch(void* const* d_in, const int* in_sizes, int n_in,
                              void* d_out, int out_size, void* d_ws, size_t ws_size,
                              hipStream_t stream)
{
    const float* x        = (const float*)d_in[0];
    const float* proj_w   = (const float*)d_in[1];
    const float* proj_b   = (const float*)d_in[2];
    const float* offset_w = (const float*)d_in[3];
    const float* offset_b = (const float*)d_in[4];
    const float* mask_w   = (const float*)d_in[5];
    const float* mask_b   = (const float*)d_in[6];
    const float* gamma    = (const float*)d_in[7];
    const float* beta     = (const float*)d_in[8];

    float* y  = (float*)d_out;                 // y lives in d_out between k2..k4
    float* ws = (float*)d_ws;
    float* offs  = ws;                         // 8*18*1024 = 147456 floats
    float* maskb = ws + 147456;                // 8*9*1024  =  73728 floats
    float* stats = ws + 147456 + 73728;        // 2*768 floats

    offmask_kernel<<<B_N * 27 * HW / 256, 256, 0, stream>>>(
        x, offset_w, offset_b, mask_w, mask_b, offs, maskb);

    dim3 g2(16, 12, B_N);                      // pixel tiles, o tiles, batch
    deform_gemm_kernel<<<g2, 256, 0, stream>>>(x, proj_w, proj_b, offs, maskb, y);

    stats_kernel<<<768, 256, 0, stream>>>(y, stats);

    finalize_kernel<<<2048, 256, 0, stream>>>(x, stats, gamma, beta, y);
}

// Round 2
// 745.501 us; speedup vs baseline: 4.4270x; 4.4270x over previous
//
#include <hip/hip_runtime.h>
#include <math.h>

typedef __attribute__((ext_vector_type(4))) float f32x4;
typedef __attribute__((ext_vector_type(8))) short s16x8;
typedef unsigned short ushort_t;

#define HW   1024
#define C_IN 768
#define B_N  8

__device__ inline ushort_t f2bf(float f) {
    unsigned u = __builtin_bit_cast(unsigned, f);
    unsigned r = u + 0x7FFFu + ((u >> 16) & 1u);
    return (ushort_t)(r >> 16);
}

// ---------------------------------------------------------------------------
// Pre-pack proj_w into MFMA A-fragment layout (bf16).
// k = tap*768 + c (tap-major). Frag: lane l holds row m=l&15, k = 8*(l>>4)+e.
// A[((s*48 + mf)*64 + lane)*8 + e],  s = K-step (216), mf = m-frag (48).
// ---------------------------------------------------------------------------
__global__ __launch_bounds__(256) void prepack_proj(
    const float* __restrict__ pw, ushort_t* __restrict__ A)
{
    int t = blockIdx.x * 256 + threadIdx.x;     // 216*48*64 = 663552 threads
    int lane = t & 63;
    int smi  = t >> 6;                          // s*48 + mf
    int s  = smi / 48, mf = smi - s * 48;
    int o  = mf * 16 + (lane & 15);
    int k0 = s * 32 + ((lane >> 4) << 3);
    int tap = k0 / 768;
    int c   = k0 - tap * 768;
    const float* src = pw + (size_t)o * 6912 + (size_t)c * 9 + tap;
    s16x8 pk;
#pragma unroll
    for (int e = 0; e < 8; ++e) pk[e] = (short)f2bf(src[e * 9]);
    *(s16x8*)(A + (size_t)smi * 512 + lane * 8) = pk;
}

// Same, for the combined 27-row offset(18)+mask(9) weight matrix, M padded to 32.
__global__ __launch_bounds__(256) void prepack_om(
    const float* __restrict__ offw, const float* __restrict__ mskw,
    ushort_t* __restrict__ A2)
{
    int t = blockIdx.x * 256 + threadIdx.x;     // 216*2*64 = 27648 threads
    int lane = t & 63;
    int smi  = t >> 6;                          // s*2 + mf
    int s  = smi >> 1, mf = smi & 1;
    int oc = mf * 16 + (lane & 15);
    int k0 = s * 32 + ((lane >> 4) << 3);
    int tap = k0 / 768;
    int c   = k0 - tap * 768;
    s16x8 pk;
#pragma unroll
    for (int e = 0; e < 8; ++e) pk[e] = 0;
    if (oc < 27) {
        const float* src = (oc < 18)
            ? offw + ((size_t)oc        * 768 + c) * 9 + tap
            : mskw + ((size_t)(oc - 18) * 768 + c) * 9 + tap;
#pragma unroll
        for (int e = 0; e < 8; ++e) pk[e] = (short)f2bf(src[e * 9]);
    }
    *(s16x8*)(A2 + (size_t)smi * 512 + lane * 8) = pk;
}

// ---------------------------------------------------------------------------
// Offset/mask conv as a small MFMA GEMM: M=32(27), N=32 px/block, K=6912.
// 4 waves, each owns one (mf,nf) 16x16 quadrant.
// ---------------------------------------------------------------------------
__global__ __launch_bounds__(256, 4) void offmask_mfma(
    const float* __restrict__ x, const ushort_t* __restrict__ A2,
    const float* __restrict__ offb, const float* __restrict__ mbias,
    float* __restrict__ offs, float* __restrict__ maskb)
{
    __shared__ __align__(16) ushort_t Bs[32 * 296];
    int bid = blockIdx.x;
    int b = bid >> 5, pt = bid & 31;
    int p0 = pt << 5;
    int t = threadIdx.x, lane = t & 63, wv = t >> 6;
    int mf = wv >> 1, nf = wv & 1;
    f32x4 acc = (f32x4){0.f, 0.f, 0.f, 0.f};

    const float* xb = x + (size_t)b * C_IN * HW;
    int j = t & 31, grp = (t >> 5) & 7;
    int px = p0 + j, h = px >> 5, w = px & 31;

    for (int st = 0; st < 24; ++st) {
        int c0 = st << 5;
#pragma unroll
        for (int tap = 0; tap < 9; ++tap) {
            int ki = tap / 3, kj = tap % 3;
            int yy = h + ki - 1, xx = w + kj - 1;
            bool ok = (yy >= 0 && yy < 32 && xx >= 0 && xx < 32);
            int src = ok ? yy * 32 + xx : 0;
#pragma unroll
            for (int q = 0; q < 2; ++q) {
                int cr = 2 * grp + (q << 4);
                const float* pl = xb + (size_t)(c0 + cr) * HW;
                float v0 = ok ? pl[src] : 0.f;
                float v1 = ok ? pl[HW + src] : 0.f;
                *(unsigned*)&Bs[j * 296 + (tap << 5) + cr] =
                    (unsigned)f2bf(v0) | ((unsigned)f2bf(v1) << 16);
            }
        }
        __syncthreads();
#pragma unroll
        for (int tap = 0; tap < 9; ++tap) {
            int s = tap * 24 + st;
            s16x8 a  = *(const s16x8*)(A2 + ((size_t)(s * 2 + mf) * 64 + lane) * 8);
            s16x8 bb = *(s16x8*)&Bs[(nf * 16 + (lane & 15)) * 296 +
                                    (tap << 5) + ((lane >> 4) << 3)];
            acc = __builtin_amdgcn_mfma_f32_16x16x32_bf16(a, bb, acc, 0, 0, 0);
        }
        __syncthreads();
    }

    int pxo = p0 + nf * 16 + (lane & 15);
#pragma unroll
    for (int r = 0; r < 4; ++r) {
        int oc = mf * 16 + ((lane >> 4) << 2) + r;
        if (oc < 18) {
            float v = acc[r] + offb[oc];
            v = fminf(fmaxf(v, -8.f), 8.f);        // max_off = 32//4
            offs[((b * 18 + oc) << 10) + pxo] = v;
        } else if (oc < 27) {
            float v = acc[r] + mbias[oc - 18];
            maskb[((b * 9 + oc - 18) << 10) + pxo] = 2.f / (1.f + expf(-v));
        }
    }
}

// ---------------------------------------------------------------------------
// Deformable conv GEMM: tile 192(o) x 64(px), 8 waves (4x2), K super-tiles of
// 32 channels x 9 taps. B built in LDS via bilinear gather (each x-plane read
// once per block); A-frags loaded global->VGPR from pre-packed layout.
// ---------------------------------------------------------------------------
__global__ __launch_bounds__(512, 4) void deform_mfma(
    const float* __restrict__ x, const ushort_t* __restrict__ A,
    const float* __restrict__ pb,
    const float* __restrict__ offs, const float* __restrict__ maskb,
    float* __restrict__ y)
{
    __shared__ __align__(16) ushort_t Bs[64 * 296];   // 37888 B
    __shared__ float4  meta_w[576];                   // 9216 B
    __shared__ ushort4 meta_i[576];                   // 4608 B

    int lid = blockIdx.x;
    int wid = (lid & 7) * 64 + (lid >> 3);    // XCD-contiguous: same otile per XCD
    int otile = wid >> 7;
    int rem = wid & 127;
    int b = rem >> 4, pt = rem & 15;
    int p0 = pt << 6;
    int t = threadIdx.x, lane = t & 63, wvid = t >> 6;
    int wm = wvid >> 1, wn = wvid & 1;

    // ---- bilinear metadata for this pixel tile ----
    for (int i = t; i < 576; i += 512) {
        int k = i >> 6, j = i & 63;
        int hw = p0 + j, h = hw >> 5, w = hw & 31;
        float dy = offs[((b * 18 + 2 * k) << 10) + hw];
        float dx = offs[((b * 18 + 2 * k + 1) << 10) + hw];
        float m  = maskb[((b * 9 + k) << 10) + hw];
        float ys = dy + (float)(h + k / 3 - 1);
        float xs = dx + (float)(w + k % 3 - 1);
        float fy = floorf(ys), fx = floorf(xs);
        float wy = ys - fy, wx = xs - fx;
        int iy0 = (int)fy, ix0 = (int)fx;
        int iy1 = iy0 + 1, ix1 = ix0 + 1;
        float vy0 = (iy0 >= 0 && iy0 < 32) ? 1.f : 0.f;
        float vy1 = (iy1 >= 0 && iy1 < 32) ? 1.f : 0.f;
        float vx0 = (ix0 >= 0 && ix0 < 32) ? 1.f : 0.f;
        float vx1 = (ix1 >= 0 && ix1 < 32) ? 1.f : 0.f;
        int cy0 = min(max(iy0, 0), 31), cx0 = min(max(ix0, 0), 31);
        int cy1 = min(max(iy1, 0), 31), cx1 = min(max(ix1, 0), 31);
        float4 wv;
        wv.x = (1.f - wy) * (1.f - wx) * m * vy0 * vx0;
        wv.y = (1.f - wy) * wx         * m * vy0 * vx1;
        wv.z = wy         * (1.f - wx) * m * vy1 * vx0;
        wv.w = wy         * wx         * m * vy1 * vx1;
        meta_w[i] = wv;
        meta_i[i] = make_ushort4((ushort_t)(cy0 * 32 + cx0), (ushort_t)(cy0 * 32 + cx1),
                                 (ushort_t)(cy1 * 32 + cx0), (ushort_t)(cy1 * 32 + cx1));
    }
    __syncthreads();

    f32x4 acc[3][2];
#pragma unroll
    for (int f = 0; f < 3; ++f)
#pragma unroll
        for (int n = 0; n < 2; ++n) acc[f][n] = (f32x4){0.f, 0.f, 0.f, 0.f};

    const float* xb = x + (size_t)b * C_IN * HW;
    const int j = lane;          // build pixel
    const int grp = wvid;        // 0..7 -> channel pairs
    const int afragbase = otile * 12 + wm * 3;

    for (int st = 0; st < 24; ++st) {
        int c0 = st << 5;
        // ---- build sampled B for 32 channels x 9 taps ----
#pragma unroll
        for (int tap = 0; tap < 9; ++tap) {
            float4  wv = meta_w[(tap << 6) + j];
            ushort4 iv = meta_i[(tap << 6) + j];
#pragma unroll
            for (int q = 0; q < 2; ++q) {
                int cr = 2 * grp + (q << 4);
                const float* pl = xb + (size_t)(c0 + cr) * HW;
                float v0 = wv.x * pl[iv.x] + wv.y * pl[iv.y] +
                           wv.z * pl[iv.z] + wv.w * pl[iv.w];
                const float* pl1 = pl + HW;
                float v1 = wv.x * pl1[iv.x] + wv.y * pl1[iv.y] +
                           wv.z * pl1[iv.z] + wv.w * pl1[iv.w];
                *(unsigned*)&Bs[j * 296 + (tap << 5) + cr] =
                    (unsigned)f2bf(v0) | ((unsigned)f2bf(v1) << 16);
            }
        }
        __syncthreads();
        // ---- 9 MFMA K-steps over the super-tile ----
#pragma unroll
        for (int tap = 0; tap < 9; ++tap) {
            int s = tap * 24 + st;
            const ushort_t* ab = A + ((size_t)(s * 48 + afragbase) * 64 + lane) * 8;
            s16x8 a0 = *(const s16x8*)ab;
            s16x8 a1 = *(const s16x8*)(ab + 512);
            s16x8 a2 = *(const s16x8*)(ab + 1024);
            int rbase = (tap << 5) + ((lane >> 4) << 3);
            s16x8 b0 = *(s16x8*)&Bs[(wn * 32 + (lane & 15)) * 296 + rbase];
            s16x8 b1 = *(s16x8*)&Bs[(wn * 32 + 16 + (lane & 15)) * 296 + rbase];
            acc[0][0] = __builtin_amdgcn_mfma_f32_16x16x32_bf16(a0, b0, acc[0][0], 0, 0, 0);
            acc[0][1] = __builtin_amdgcn_mfma_f32_16x16x32_bf16(a0, b1, acc[0][1], 0, 0, 0);
            acc[1][0] = __builtin_amdgcn_mfma_f32_16x16x32_bf16(a1, b0, acc[1][0], 0, 0, 0);
            acc[1][1] = __builtin_amdgcn_mfma_f32_16x16x32_bf16(a1, b1, acc[1][1], 0, 0, 0);
            acc[2][0] = __builtin_amdgcn_mfma_f32_16x16x32_bf16(a2, b0, acc[2][0], 0, 0, 0);
            acc[2][1] = __builtin_amdgcn_mfma_f32_16x16x32_bf16(a2, b1, acc[2][1], 0, 0, 0);
        }
        __syncthreads();
    }

    // ---- epilogue: +bias, fp32 store ----
    int pxo = p0 + wn * 32 + (lane & 15);
    int obase = otile * 192 + wm * 48;
#pragma unroll
    for (int f = 0; f < 3; ++f) {
        int orow = obase + f * 16 + ((lane >> 4) << 2);
#pragma unroll
        for (int r = 0; r < 4; ++r) {
            float bias = pb[orow + r];
            size_t rowoff = ((size_t)(b * 768 + orow + r) << 10);
            y[rowoff + pxo]      = acc[f][0][r] + bias;
            y[rowoff + pxo + 16] = acc[f][1][r] + bias;
        }
    }
}

// ---------------------------------------------------------------------------
// Per-channel mean / rstd over (B, H, W)
// ---------------------------------------------------------------------------
__global__ __launch_bounds__(256) void stats_kernel(
    const float* __restrict__ y, float* __restrict__ stats)
{
    int o = blockIdx.x;
    int tid = threadIdx.x;
    float s1 = 0.f, s2 = 0.f;
    for (int i = tid; i < B_N * HW; i += 256) {
        int b = i >> 10, hw = i & 1023;
        float v = y[(((size_t)b * 768 + o) << 10) + hw];
        s1 += v; s2 += v * v;
    }
#pragma unroll
    for (int off = 32; off > 0; off >>= 1) {
        s1 += __shfl_down(s1, off);
        s2 += __shfl_down(s2, off);
    }
    __shared__ float ls1[4], ls2[4];
    int wid = tid >> 6, lane = tid & 63;
    if (lane == 0) { ls1[wid] = s1; ls2[wid] = s2; }
    __syncthreads();
    if (tid == 0) {
        float t1 = ls1[0] + ls1[1] + ls1[2] + ls1[3];
        float t2 = ls2[0] + ls2[1] + ls2[2] + ls2[3];
        float mean = t1 * (1.0f / 8192.0f);
        float var  = t2 * (1.0f / 8192.0f) - mean * mean;
        stats[o]       = mean;
        stats[768 + o] = 1.0f / sqrtf(var + 1e-5f);
    }
}

// ---------------------------------------------------------------------------
// normalize + exact GELU + residual, in-place on y (= d_out)
// ---------------------------------------------------------------------------
__global__ __launch_bounds__(256) void finalize_kernel(
    const float* __restrict__ x, const float* __restrict__ stats,
    const float* __restrict__ gamma, const float* __restrict__ beta,
    float* __restrict__ y)
{
    const int total4 = B_N * 768 * HW / 4;
    for (int f = blockIdx.x * 256 + threadIdx.x; f < total4;
         f += gridDim.x * 256) {
        int e = f << 2;
        int o = (e >> 10) % 768;
        float mean = stats[o], rstd = stats[768 + o];
        float ga = gamma[o], be = beta[o];
        float4 v  = ((const float4*)y)[f];
        float4 xv = ((const float4*)x)[f];
        float4 r;
        {
            float yn = (v.x - mean) * rstd * ga + be;
            r.x = xv.x + 0.5f * yn * (1.0f + erff(yn * 0.70710678f));
        }
        {
            float yn = (v.y - mean) * rstd * ga + be;
            r.y = xv.y + 0.5f * yn * (1.0f + erff(yn * 0.70710678f));
        }
        {
            float yn = (v.z - mean) * rstd * ga + be;
            r.z = xv.z + 0.5f * yn * (1.0f + erff(yn * 0.70710678f));
        }
        {
            float yn = (v.w - mean) * rstd * ga + be;
            r.w = xv.w + 0.5f * yn * (1.0f + erff(yn * 0.70710678f));
        }
        ((float4*)y)[f] = r;
    }
}

// ---------------------------------------------------------------------------
extern "C" void kernel_launch(void* const* d_in, const int* in_sizes, int n_in,
                              void* d_out, int out_size, void* d_ws, size_t ws_size,
                              hipStream_t stream)
{
    const float* x        = (const float*)d_in[0];
    const float* proj_w   = (const float*)d_in[1];
    const float* proj_b   = (const float*)d_in[2];
    const float* offset_w = (const float*)d_in[3];
    const float* offset_b = (const float*)d_in[4];
    const float* mask_w   = (const float*)d_in[5];
    const float* mask_b   = (const float*)d_in[6];
    const float* gamma    = (const float*)d_in[7];
    const float* beta     = (const float*)d_in[8];

    char* ws = (char*)d_ws;
    float*    offs  = (float*)(ws);                  // 8*18*1024 f = 589824 B
    float*    maskb = (float*)(ws + 589824);         // 8*9*1024 f  = 294912 B
    float*    stats = (float*)(ws + 884736);         // 1536 f      = 6144 B
    ushort_t* A     = (ushort_t*)(ws + 890880);      // 216*48*512  = 10616832 B
    ushort_t* A2    = (ushort_t*)(ws + 11507712);    // 216*2*512   = 442368 B
    float* y = (float*)d_out;

    prepack_proj<<<2592, 256, 0, stream>>>(proj_w, A);
    prepack_om<<<108, 256, 0, stream>>>(offset_w, mask_w, A2);
    offmask_mfma<<<256, 256, 0, stream>>>(x, A2, offset_b, mask_b, offs, maskb);
    deform_mfma<<<512, 512, 0, stream>>>(x, A, proj_b, offs, maskb, y);
    stats_kernel<<<768, 256, 0, stream>>>(y, stats);
    finalize_kernel<<<2048, 256, 0, stream>>>(x, stats, gamma, beta, y);
}

// Round 3
// 369.047 us; speedup vs baseline: 8.9429x; 2.0201x over previous
//
#include <hip/hip_runtime.h>
#include <math.h>

typedef __attribute__((ext_vector_type(4))) float f32x4;
typedef __attribute__((ext_vector_type(8))) short s16x8;
typedef __attribute__((ext_vector_type(4))) unsigned int u32x4;
typedef unsigned short ushort_t;

#define HW   1024
#define C_IN 768
#define B_N  8

__device__ inline ushort_t f2bf(float f) {
    unsigned u = __builtin_bit_cast(unsigned, f);
    unsigned r = u + 0x7FFFu + ((u >> 16) & 1u);
    return (ushort_t)(r >> 16);
}
__device__ inline unsigned pk2bf(float f0, float f1) {
    unsigned u0 = __builtin_bit_cast(unsigned, f0);
    unsigned u1 = __builtin_bit_cast(unsigned, f1);
    u0 += 0x7FFFu + ((u0 >> 16) & 1u);
    u1 += 0x7FFFu + ((u1 >> 16) & 1u);
    return (u0 >> 16) | (u1 & 0xFFFF0000u);
}
__device__ inline float bf2f(short s) {
    return __builtin_bit_cast(float, ((unsigned)(ushort_t)s) << 16);
}

// ---------------------------------------------------------------------------
// x [b][c][pos] fp32  ->  xt [b][pos][c] bf16   (row = 768 ch = 1536 B)
// ---------------------------------------------------------------------------
__global__ __launch_bounds__(256) void prepack_xt(
    const float* __restrict__ x, ushort_t* __restrict__ xt)
{
    __shared__ ushort_t tile[64][66];
    int bid = blockIdx.x;                 // 8 * 12 * 16
    int b  = bid / 192;
    int r  = bid % 192;
    int cg = r / 16, pg = r % 16;
    int c0 = cg * 64, p0 = pg * 64;
    int t = threadIdx.x;
#pragma unroll
    for (int i = 0; i < 16; ++i) {
        int idx = t + i * 256;
        int cr = idx >> 6, col = idx & 63;
        tile[cr][col] = f2bf(x[(((size_t)b * C_IN + c0 + cr) << 10) + p0 + col]);
    }
    __syncthreads();
#pragma unroll
    for (int i = 0; i < 16; ++i) {
        int idx = t + i * 256;
        int pr = idx >> 6, col = idx & 63;
        xt[((size_t)(b << 10) + p0 + pr) * C_IN + c0 + col] = tile[col][pr];
    }
}

// ---------------------------------------------------------------------------
// proj_w -> MFMA A-frag layout, k = tap*768 + c (tap-major).
// ---------------------------------------------------------------------------
__global__ __launch_bounds__(256) void prepack_proj(
    const float* __restrict__ pw, ushort_t* __restrict__ A)
{
    int t = blockIdx.x * 256 + threadIdx.x;     // 216*48*64 threads
    int lane = t & 63;
    int smi  = t >> 6;
    int s  = smi / 48, mf = smi - s * 48;
    int o  = mf * 16 + (lane & 15);
    int k0 = s * 32 + ((lane >> 4) << 3);
    int tap = k0 / 768;
    int c   = k0 - tap * 768;
    const float* src = pw + (size_t)o * 6912 + (size_t)c * 9 + tap;
    s16x8 pk;
#pragma unroll
    for (int e = 0; e < 8; ++e) pk[e] = (short)f2bf(src[e * 9]);
    *(s16x8*)(A + (size_t)smi * 512 + lane * 8) = pk;
}

__global__ __launch_bounds__(256) void prepack_om(
    const float* __restrict__ offw, const float* __restrict__ mskw,
    ushort_t* __restrict__ A2)
{
    int t = blockIdx.x * 256 + threadIdx.x;     // 216*2*64 threads
    int lane = t & 63;
    int smi  = t >> 6;
    int s  = smi >> 1, mf = smi & 1;
    int oc = mf * 16 + (lane & 15);
    int k0 = s * 32 + ((lane >> 4) << 3);
    int tap = k0 / 768;
    int c   = k0 - tap * 768;
    s16x8 pk;
#pragma unroll
    for (int e = 0; e < 8; ++e) pk[e] = 0;
    if (oc < 27) {
        const float* src = (oc < 18)
            ? offw + ((size_t)oc        * 768 + c) * 9 + tap
            : mskw + ((size_t)(oc - 18) * 768 + c) * 9 + tap;
#pragma unroll
        for (int e = 0; e < 8; ++e) pk[e] = (short)f2bf(src[e * 9]);
    }
    *(s16x8*)(A2 + (size_t)smi * 512 + lane * 8) = pk;
}

// ---------------------------------------------------------------------------
// Offset/mask conv: LDS-free MFMA GEMM. B-frags are 16B contiguous in xt.
// M=32(27), N=32 px/block, 4 waves = (mf,nf) quadrants.
// ---------------------------------------------------------------------------
__global__ __launch_bounds__(256) void offmask_mfma(
    const ushort_t* __restrict__ xt, const ushort_t* __restrict__ A2,
    const float* __restrict__ offb, const float* __restrict__ mbias,
    float* __restrict__ offs, float* __restrict__ maskb)
{
    int bid = blockIdx.x;               // b*32 + pt
    int b = bid >> 5, pt = bid & 31;
    int p0 = pt << 5;
    int t = threadIdx.x, lane = t & 63, wv = t >> 6;
    int mf = wv >> 1, nf = wv & 1;
    int q = lane >> 4;
    int px = p0 + nf * 16 + (lane & 15);
    int h = px >> 5, w = px & 31;
    const char* xb = (const char*)xt + (size_t)b * (HW * 1536);
    f32x4 acc = (f32x4){0.f, 0.f, 0.f, 0.f};

    for (int tap = 0; tap < 9; ++tap) {
        int yy = h + tap / 3 - 1, xx = w + tap % 3 - 1;
        bool ok = (yy >= 0 && yy < 32 && xx >= 0 && xx < 32);
        int pos = ok ? (yy * 32 + xx) : 0;
        const char* bp = xb + (size_t)pos * 1536 + q * 16;
        for (int cs = 0; cs < 24; ++cs) {
            int s = tap * 24 + cs;
            s16x8 bf;
            if (ok) bf = *(const s16x8*)(bp + cs * 64);
            else    bf = (s16x8){0, 0, 0, 0, 0, 0, 0, 0};
            s16x8 af = *(const s16x8*)(A2 + ((size_t)(s * 2 + mf) * 64 + lane) * 8);
            acc = __builtin_amdgcn_mfma_f32_16x16x32_bf16(af, bf, acc, 0, 0, 0);
        }
    }
#pragma unroll
    for (int r = 0; r < 4; ++r) {
        int oc = mf * 16 + ((lane >> 4) << 2) + r;
        if (oc < 18) {
            float v = acc[r] + offb[oc];
            v = fminf(fmaxf(v, -8.f), 8.f);        // max_off = 32//4
            offs[((b * 18 + oc) << 10) + px] = v;
        } else if (oc < 27) {
            float v = acc[r] + mbias[oc - 18];
            maskb[((b * 9 + oc - 18) << 10) + px] = 2.f / (1.f + expf(-v));
        }
    }
}

// ---------------------------------------------------------------------------
// Deformable conv GEMM, tile 192(o) x 64(px), 8 waves (4 wm x 2 wn).
// 108 phases: (tap, 64-ch step). Build: 1 octet/thread via 4x16B NHWC gathers,
// double-buffered; gathers for phase p+1 issue before MFMA of phase p.
// ---------------------------------------------------------------------------
__global__ __launch_bounds__(512, 4) void deform_mfma(
    const ushort_t* __restrict__ xt, const ushort_t* __restrict__ A,
    const float* __restrict__ offs, const float* __restrict__ maskb,
    float* __restrict__ y)
{
    __shared__ float4 meta_w[576];
    __shared__ int4   meta_i[576];
    __shared__ __align__(16) ushort_t Bs[2][64][72];   // 144B row: ~2-way (free)

    int id = blockIdx.x;                  // b low 3 bits -> XCD keeps xt_b local
    int b = id & 7;
    int pxt = (id >> 3) & 15;
    int otile = id >> 7;
    int p0 = pxt << 6;
    int t = threadIdx.x, lane = t & 63, wv = t >> 6;
    int wm = wv >> 1, wn = wv & 1;
    int q = lane >> 4;

    // ---- bilinear metadata (64 px x 9 taps), byte offsets into xt rows ----
    for (int i = t; i < 576; i += 512) {
        int k = i >> 6, j = i & 63;
        int hw = p0 + j, h = hw >> 5, w = hw & 31;
        float dy = offs[((b * 18 + 2 * k) << 10) + hw];
        float dx = offs[((b * 18 + 2 * k + 1) << 10) + hw];
        float m  = maskb[((b * 9 + k) << 10) + hw];
        float ys = dy + (float)(h + k / 3 - 1);
        float xs = dx + (float)(w + k % 3 - 1);
        float fy = floorf(ys), fx = floorf(xs);
        float wy = ys - fy, wx = xs - fx;
        int iy0 = (int)fy, ix0 = (int)fx;
        int iy1 = iy0 + 1, ix1 = ix0 + 1;
        float vy0 = (iy0 >= 0 && iy0 < 32) ? 1.f : 0.f;
        float vy1 = (iy1 >= 0 && iy1 < 32) ? 1.f : 0.f;
        float vx0 = (ix0 >= 0 && ix0 < 32) ? 1.f : 0.f;
        float vx1 = (ix1 >= 0 && ix1 < 32) ? 1.f : 0.f;
        int cy0 = min(max(iy0, 0), 31), cx0 = min(max(ix0, 0), 31);
        int cy1 = min(max(iy1, 0), 31), cx1 = min(max(ix1, 0), 31);
        float4 wv4;
        wv4.x = (1.f - wy) * (1.f - wx) * m * vy0 * vx0;
        wv4.y = (1.f - wy) * wx         * m * vy0 * vx1;
        wv4.z = wy         * (1.f - wx) * m * vy1 * vx0;
        wv4.w = wy         * wx         * m * vy1 * vx1;
        meta_w[i] = wv4;
        meta_i[i] = make_int4((cy0 * 32 + cx0) * 1536, (cy0 * 32 + cx1) * 1536,
                              (cy1 * 32 + cx0) * 1536, (cy1 * 32 + cx1) * 1536);
    }
    __syncthreads();

    f32x4 acc[3][2];
#pragma unroll
    for (int f = 0; f < 3; ++f)
#pragma unroll
        for (int n = 0; n < 2; ++n) acc[f][n] = (f32x4){0.f, 0.f, 0.f, 0.f};

    const char* xb = (const char*)xt + (size_t)b * (HW * 1536);
    const int afrag0 = otile * 12 + wm * 3;

    // ---- prologue: build phase 0 into buf 0 ----
    {
        float4 w4 = meta_w[lane];
        int4  i4 = meta_i[lane];
        const char* base = xb + wv * 16;
        s16x8 g0 = *(const s16x8*)(base + i4.x);
        s16x8 g1 = *(const s16x8*)(base + i4.y);
        s16x8 g2 = *(const s16x8*)(base + i4.z);
        s16x8 g3 = *(const s16x8*)(base + i4.w);
        u32x4 bw;
#pragma unroll
        for (int e2 = 0; e2 < 4; ++e2) {
            float v0 = w4.x * bf2f(g0[2 * e2])     + w4.y * bf2f(g1[2 * e2])
                     + w4.z * bf2f(g2[2 * e2])     + w4.w * bf2f(g3[2 * e2]);
            float v1 = w4.x * bf2f(g0[2 * e2 + 1]) + w4.y * bf2f(g1[2 * e2 + 1])
                     + w4.z * bf2f(g2[2 * e2 + 1]) + w4.w * bf2f(g3[2 * e2 + 1]);
            bw[e2] = pk2bf(v0, v1);
        }
        *(u32x4*)&Bs[0][lane][wv * 8] = bw;
    }
    __syncthreads();

    for (int p = 0; p < 108; ++p) {
        int tap = p / 12, cs = p - tap * 12;
        int buf = p & 1;
        // ---- issue gathers for phase p+1 (latency hides under MFMA) ----
        s16x8 g0, g1, g2, g3;
        float4 w4n;
        bool have = (p + 1 < 108);
        if (have) {
            int pn = p + 1;
            int ntap = pn / 12, ncs = pn - ntap * 12;
            w4n = meta_w[ntap * 64 + lane];
            int4 i4 = meta_i[ntap * 64 + lane];
            const char* base = xb + ncs * 128 + wv * 16;
            g0 = *(const s16x8*)(base + i4.x);
            g1 = *(const s16x8*)(base + i4.y);
            g2 = *(const s16x8*)(base + i4.z);
            g3 = *(const s16x8*)(base + i4.w);
        }
        // ---- MFMA phase p: 2 K-steps over buf ----
#pragma unroll
        for (int kk = 0; kk < 2; ++kk) {
            int s = tap * 24 + cs * 2 + kk;
            const s16x8* ap = (const s16x8*)(A + ((size_t)(s * 48 + afrag0) * 64 + lane) * 8);
            s16x8 a0 = ap[0];
            s16x8 a1 = ap[64];
            s16x8 a2 = ap[128];
            const ushort_t* brow = &Bs[buf][wn * 32 + (lane & 15)][kk * 32 + q * 8];
            s16x8 b0 = *(const s16x8*)brow;
            s16x8 b1 = *(const s16x8*)(brow + 16 * 72);
            acc[0][0] = __builtin_amdgcn_mfma_f32_16x16x32_bf16(a0, b0, acc[0][0], 0, 0, 0);
            acc[0][1] = __builtin_amdgcn_mfma_f32_16x16x32_bf16(a0, b1, acc[0][1], 0, 0, 0);
            acc[1][0] = __builtin_amdgcn_mfma_f32_16x16x32_bf16(a1, b0, acc[1][0], 0, 0, 0);
            acc[1][1] = __builtin_amdgcn_mfma_f32_16x16x32_bf16(a1, b1, acc[1][1], 0, 0, 0);
            acc[2][0] = __builtin_amdgcn_mfma_f32_16x16x32_bf16(a2, b0, acc[2][0], 0, 0, 0);
            acc[2][1] = __builtin_amdgcn_mfma_f32_16x16x32_bf16(a2, b1, acc[2][1], 0, 0, 0);
        }
        // ---- build phase p+1 into buf^1 ----
        if (have) {
            u32x4 bw;
#pragma unroll
            for (int e2 = 0; e2 < 4; ++e2) {
                float v0 = w4n.x * bf2f(g0[2 * e2])     + w4n.y * bf2f(g1[2 * e2])
                         + w4n.z * bf2f(g2[2 * e2])     + w4n.w * bf2f(g3[2 * e2]);
                float v1 = w4n.x * bf2f(g0[2 * e2 + 1]) + w4n.y * bf2f(g1[2 * e2 + 1])
                         + w4n.z * bf2f(g2[2 * e2 + 1]) + w4n.w * bf2f(g3[2 * e2 + 1]);
                bw[e2] = pk2bf(v0, v1);
            }
            *(u32x4*)&Bs[buf ^ 1][lane][wv * 8] = bw;
        }
        __syncthreads();
    }

    // ---- epilogue (no bias: per-channel bias cancels in batch-norm) ----
    int pxo = p0 + wn * 32 + (lane & 15);
    int obase = otile * 192 + wm * 48;
#pragma unroll
    for (int f = 0; f < 3; ++f) {
        int orow = obase + f * 16 + ((lane >> 4) << 2);
#pragma unroll
        for (int r = 0; r < 4; ++r) {
            size_t rowoff = ((size_t)(b * 768 + orow + r) << 10);
            y[rowoff + pxo]      = acc[f][0][r];
            y[rowoff + pxo + 16] = acc[f][1][r];
        }
    }
}

// ---------------------------------------------------------------------------
__global__ __launch_bounds__(256) void stats_kernel(
    const float* __restrict__ y, float* __restrict__ stats)
{
    int o = blockIdx.x;
    int tid = threadIdx.x;
    float s1 = 0.f, s2 = 0.f;
    for (int i = tid; i < B_N * HW; i += 256) {
        int b = i >> 10, hw = i & 1023;
        float v = y[(((size_t)b * 768 + o) << 10) + hw];
        s1 += v; s2 += v * v;
    }
#pragma unroll
    for (int off = 32; off > 0; off >>= 1) {
        s1 += __shfl_down(s1, off);
        s2 += __shfl_down(s2, off);
    }
    __shared__ float ls1[4], ls2[4];
    int wid = tid >> 6, lane = tid & 63;
    if (lane == 0) { ls1[wid] = s1; ls2[wid] = s2; }
    __syncthreads();
    if (tid == 0) {
        float t1 = ls1[0] + ls1[1] + ls1[2] + ls1[3];
        float t2 = ls2[0] + ls2[1] + ls2[2] + ls2[3];
        float mean = t1 * (1.0f / 8192.0f);
        float var  = t2 * (1.0f / 8192.0f) - mean * mean;
        stats[o]       = mean;
        stats[768 + o] = 1.0f / sqrtf(var + 1e-5f);
    }
}

__global__ __launch_bounds__(256) void finalize_kernel(
    const float* __restrict__ x, const float* __restrict__ stats,
    const float* __restrict__ gamma, const float* __restrict__ beta,
    float* __restrict__ y)
{
    const int total4 = B_N * 768 * HW / 4;
    for (int f = blockIdx.x * 256 + threadIdx.x; f < total4;
         f += gridDim.x * 256) {
        int e = f << 2;
        int o = (e >> 10) % 768;
        float mean = stats[o], rstd = stats[768 + o];
        float ga = gamma[o], be = beta[o];
        float4 v  = ((const float4*)y)[f];
        float4 xv = ((const float4*)x)[f];
        float4 r;
        {
            float yn = (v.x - mean) * rstd * ga + be;
            r.x = xv.x + 0.5f * yn * (1.0f + erff(yn * 0.70710678f));
        }
        {
            float yn = (v.y - mean) * rstd * ga + be;
            r.y = xv.y + 0.5f * yn * (1.0f + erff(yn * 0.70710678f));
        }
        {
            float yn = (v.z - mean) * rstd * ga + be;
            r.z = xv.z + 0.5f * yn * (1.0f + erff(yn * 0.70710678f));
        }
        {
            float yn = (v.w - mean) * rstd * ga + be;
            r.w = xv.w + 0.5f * yn * (1.0f + erff(yn * 0.70710678f));
        }
        ((float4*)y)[f] = r;
    }
}

// ---------------------------------------------------------------------------
extern "C" void kernel_launch(void* const* d_in, const int* in_sizes, int n_in,
                              void* d_out, int out_size, void* d_ws, size_t ws_size,
                              hipStream_t stream)
{
    const float* x        = (const float*)d_in[0];
    const float* proj_w   = (const float*)d_in[1];
    const float* offset_w = (const float*)d_in[3];
    const float* offset_b = (const float*)d_in[4];
    const float* mask_w   = (const float*)d_in[5];
    const float* mask_b   = (const float*)d_in[6];
    const float* gamma    = (const float*)d_in[7];
    const float* beta     = (const float*)d_in[8];

    char* ws = (char*)d_ws;
    float*    offs  = (float*)(ws);                  //   589824 B
    float*    maskb = (float*)(ws + 589824);         //   294912 B
    float*    stats = (float*)(ws + 884736);         //     6144 B
    ushort_t* A     = (ushort_t*)(ws + 890880);      // 10616832 B
    ushort_t* A2    = (ushort_t*)(ws + 11507712);    //   442368 B
    ushort_t* xt    = (ushort_t*)(ws + 11950080);    // 12582912 B  (tot ~24.5MB)
    float* y = (float*)d_out;

    prepack_xt<<<1536, 256, 0, stream>>>(x, xt);
    prepack_om<<<108, 256, 0, stream>>>(offset_w, mask_w, A2);
    prepack_proj<<<2592, 256, 0, stream>>>(proj_w, A);
    offmask_mfma<<<256, 256, 0, stream>>>(xt, A2, offset_b, mask_b, offs, maskb);
    deform_mfma<<<512, 512, 0, stream>>>(xt, A, offs, maskb, y);
    stats_kernel<<<768, 256, 0, stream>>>(y, stats);
    finalize_kernel<<<2048, 256, 0, stream>>>(x, stats, gamma, beta, y);
}

// Round 4
// 286.741 us; speedup vs baseline: 11.5099x; 1.2870x over previous
//
#include <hip/hip_runtime.h>
#include <math.h>

typedef __attribute__((ext_vector_type(4))) float f32x4;
typedef __attribute__((ext_vector_type(8))) short s16x8;
typedef __attribute__((ext_vector_type(4))) unsigned int u32x4;
typedef unsigned short ushort_t;

#define HW   1024
#define C_IN 768
#define B_N  8

__device__ inline ushort_t f2bf(float f) {
    unsigned u = __builtin_bit_cast(unsigned, f);
    unsigned r = u + 0x7FFFu + ((u >> 16) & 1u);
    return (ushort_t)(r >> 16);
}
__device__ inline unsigned pk2bf(float f0, float f1) {
    unsigned u0 = __builtin_bit_cast(unsigned, f0);
    unsigned u1 = __builtin_bit_cast(unsigned, f1);
    u0 += 0x7FFFu + ((u0 >> 16) & 1u);
    u1 += 0x7FFFu + ((u1 >> 16) & 1u);
    return (u0 >> 16) | (u1 & 0xFFFF0000u);
}
__device__ inline float bf2f(short s) {
    return __builtin_bit_cast(float, ((unsigned)(ushort_t)s) << 16);
}

// ---------------------------------------------------------------------------
// x [b][c][pos] fp32  ->  xt [b][pos][c] bf16   (row = 768 ch = 1536 B)
// ---------------------------------------------------------------------------
__global__ __launch_bounds__(256) void prepack_xt(
    const float* __restrict__ x, ushort_t* __restrict__ xt)
{
    __shared__ ushort_t tile[64][66];
    int bid = blockIdx.x;                 // 8 * 12 * 16
    int b  = bid / 192;
    int r  = bid % 192;
    int cg = r / 16, pg = r % 16;
    int c0 = cg * 64, p0 = pg * 64;
    int t = threadIdx.x;
#pragma unroll
    for (int i = 0; i < 16; ++i) {
        int idx = t + i * 256;
        int cr = idx >> 6, col = idx & 63;
        tile[cr][col] = f2bf(x[(((size_t)b * C_IN + c0 + cr) << 10) + p0 + col]);
    }
    __syncthreads();
#pragma unroll
    for (int i = 0; i < 16; ++i) {
        int idx = t + i * 256;
        int pr = idx >> 6, col = idx & 63;
        xt[((size_t)(b << 10) + p0 + pr) * C_IN + c0 + col] = tile[col][pr];
    }
}

// ---------------------------------------------------------------------------
// proj_w -> MFMA A-frag layout, k = tap*768 + c (tap-major).
// ---------------------------------------------------------------------------
__global__ __launch_bounds__(256) void prepack_proj(
    const float* __restrict__ pw, ushort_t* __restrict__ A)
{
    int t = blockIdx.x * 256 + threadIdx.x;     // 216*48*64 threads
    int lane = t & 63;
    int smi  = t >> 6;
    int s  = smi / 48, mf = smi - s * 48;
    int o  = mf * 16 + (lane & 15);
    int k0 = s * 32 + ((lane >> 4) << 3);
    int tap = k0 / 768;
    int c   = k0 - tap * 768;
    const float* src = pw + (size_t)o * 6912 + (size_t)c * 9 + tap;
    s16x8 pk;
#pragma unroll
    for (int e = 0; e < 8; ++e) pk[e] = (short)f2bf(src[e * 9]);
    *(s16x8*)(A + (size_t)smi * 512 + lane * 8) = pk;
}

__global__ __launch_bounds__(256) void prepack_om(
    const float* __restrict__ offw, const float* __restrict__ mskw,
    ushort_t* __restrict__ A2)
{
    int t = blockIdx.x * 256 + threadIdx.x;     // 216*2*64 threads
    int lane = t & 63;
    int smi  = t >> 6;
    int s  = smi >> 1, mf = smi & 1;
    int oc = mf * 16 + (lane & 15);
    int k0 = s * 32 + ((lane >> 4) << 3);
    int tap = k0 / 768;
    int c   = k0 - tap * 768;
    s16x8 pk;
#pragma unroll
    for (int e = 0; e < 8; ++e) pk[e] = 0;
    if (oc < 27) {
        const float* src = (oc < 18)
            ? offw + ((size_t)oc        * 768 + c) * 9 + tap
            : mskw + ((size_t)(oc - 18) * 768 + c) * 9 + tap;
#pragma unroll
        for (int e = 0; e < 8; ++e) pk[e] = (short)f2bf(src[e * 9]);
    }
    *(s16x8*)(A2 + (size_t)smi * 512 + lane * 8) = pk;
}

// ---------------------------------------------------------------------------
// Offset/mask conv: LDS-free MFMA GEMM. B-frags are 16B contiguous in xt.
// ---------------------------------------------------------------------------
__global__ __launch_bounds__(256) void offmask_mfma(
    const ushort_t* __restrict__ xt, const ushort_t* __restrict__ A2,
    const float* __restrict__ offb, const float* __restrict__ mbias,
    float* __restrict__ offs, float* __restrict__ maskb)
{
    int bid = blockIdx.x;               // b*32 + pt
    int b = bid >> 5, pt = bid & 31;
    int p0 = pt << 5;
    int t = threadIdx.x, lane = t & 63, wv = t >> 6;
    int mf = wv >> 1, nf = wv & 1;
    int q = lane >> 4;
    int px = p0 + nf * 16 + (lane & 15);
    int h = px >> 5, w = px & 31;
    const char* xb = (const char*)xt + (size_t)b * (HW * 1536);
    f32x4 acc = (f32x4){0.f, 0.f, 0.f, 0.f};

    for (int tap = 0; tap < 9; ++tap) {
        int yy = h + tap / 3 - 1, xx = w + tap % 3 - 1;
        bool ok = (yy >= 0 && yy < 32 && xx >= 0 && xx < 32);
        int pos = ok ? (yy * 32 + xx) : 0;
        const char* bp = xb + (size_t)pos * 1536 + q * 16;
        for (int cs = 0; cs < 24; ++cs) {
            int s = tap * 24 + cs;
            s16x8 bf;
            if (ok) bf = *(const s16x8*)(bp + cs * 64);
            else    bf = (s16x8){0, 0, 0, 0, 0, 0, 0, 0};
            s16x8 af = *(const s16x8*)(A2 + ((size_t)(s * 2 + mf) * 64 + lane) * 8);
            acc = __builtin_amdgcn_mfma_f32_16x16x32_bf16(af, bf, acc, 0, 0, 0);
        }
    }
#pragma unroll
    for (int r = 0; r < 4; ++r) {
        int oc = mf * 16 + ((lane >> 4) << 2) + r;
        if (oc < 18) {
            float v = acc[r] + offb[oc];
            v = fminf(fmaxf(v, -8.f), 8.f);        // max_off = 32//4
            offs[((b * 18 + oc) << 10) + px] = v;
        } else if (oc < 27) {
            float v = acc[r] + mbias[oc - 18];
            maskb[((b * 9 + oc - 18) << 10) + px] = 2.f / (1.f + expf(-v));
        }
    }
}

// ---------------------------------------------------------------------------
// Deformable conv GEMM, tile 192(o) x 64(px), 8 waves (4 wm x 2 wn).
// 108 phases: (tap, 64-ch step). Build lane map: 8 lanes cover the 64-ch span
// of ONE pixel-neighbor (bpx = wv*8 + lane>>3, oct = lane&7) -> each gather
// instr touches 8 x 128B contiguous clusters (16 lines) instead of 64 rows.
// Bs chunks XOR-swizzled by (row&7) to keep LDS conflicts <=2-way.
// ---------------------------------------------------------------------------
__global__ __launch_bounds__(512, 4) void deform_mfma(
    const ushort_t* __restrict__ xt, const ushort_t* __restrict__ A,
    const float* __restrict__ offs, const float* __restrict__ maskb,
    float* __restrict__ y)
{
    __shared__ float4 meta_w[576];
    __shared__ int4   meta_i[576];
    __shared__ __align__(16) ushort_t Bs[2][64][72];

    int id = blockIdx.x;                  // b = id&7 == XCD -> xt slab L2-local
    int b = id & 7;
    int pxt = (id >> 3) & 15;
    int otile = id >> 7;
    int p0 = pxt << 6;
    int t = threadIdx.x, lane = t & 63, wv = t >> 6;
    int wm = wv >> 1, wn = wv & 1;
    int q = lane >> 4;

    // build-phase lane map
    int bpx = wv * 8 + (lane >> 3);       // 0..63 pixel
    int oct = lane & 7;                   // 0..7 channel-octet (16B)

    // ---- bilinear metadata (64 px x 9 taps), byte offsets into xt rows ----
    for (int i = t; i < 576; i += 512) {
        int k = i >> 6, j = i & 63;
        int hw = p0 + j, h = hw >> 5, w = hw & 31;
        float dy = offs[((b * 18 + 2 * k) << 10) + hw];
        float dx = offs[((b * 18 + 2 * k + 1) << 10) + hw];
        float m  = maskb[((b * 9 + k) << 10) + hw];
        float ys = dy + (float)(h + k / 3 - 1);
        float xs = dx + (float)(w + k % 3 - 1);
        float fy = floorf(ys), fx = floorf(xs);
        float wy = ys - fy, wx = xs - fx;
        int iy0 = (int)fy, ix0 = (int)fx;
        int iy1 = iy0 + 1, ix1 = ix0 + 1;
        float vy0 = (iy0 >= 0 && iy0 < 32) ? 1.f : 0.f;
        float vy1 = (iy1 >= 0 && iy1 < 32) ? 1.f : 0.f;
        float vx0 = (ix0 >= 0 && ix0 < 32) ? 1.f : 0.f;
        float vx1 = (ix1 >= 0 && ix1 < 32) ? 1.f : 0.f;
        int cy0 = min(max(iy0, 0), 31), cx0 = min(max(ix0, 0), 31);
        int cy1 = min(max(iy1, 0), 31), cx1 = min(max(ix1, 0), 31);
        float4 wv4;
        wv4.x = (1.f - wy) * (1.f - wx) * m * vy0 * vx0;
        wv4.y = (1.f - wy) * wx         * m * vy0 * vx1;
        wv4.z = wy         * (1.f - wx) * m * vy1 * vx0;
        wv4.w = wy         * wx         * m * vy1 * vx1;
        meta_w[i] = wv4;
        meta_i[i] = make_int4((cy0 * 32 + cx0) * 1536, (cy0 * 32 + cx1) * 1536,
                              (cy1 * 32 + cx0) * 1536, (cy1 * 32 + cx1) * 1536);
    }
    __syncthreads();

    f32x4 acc[3][2];
#pragma unroll
    for (int f = 0; f < 3; ++f)
#pragma unroll
        for (int n = 0; n < 2; ++n) acc[f][n] = (f32x4){0.f, 0.f, 0.f, 0.f};

    const char* xb = (const char*)xt + (size_t)b * (HW * 1536);
    const int afrag0 = otile * 12 + wm * 3;
    const int wchunk = (oct ^ (bpx & 7)) * 8;    // swizzled write chunk

    // ---- prologue: build phase 0 into buf 0 ----
    {
        float4 w4 = meta_w[bpx];
        int4  i4 = meta_i[bpx];
        const char* base = xb + oct * 16;
        s16x8 g0 = *(const s16x8*)(base + i4.x);
        s16x8 g1 = *(const s16x8*)(base + i4.y);
        s16x8 g2 = *(const s16x8*)(base + i4.z);
        s16x8 g3 = *(const s16x8*)(base + i4.w);
        u32x4 bw;
#pragma unroll
        for (int e2 = 0; e2 < 4; ++e2) {
            float v0 = w4.x * bf2f(g0[2 * e2])     + w4.y * bf2f(g1[2 * e2])
                     + w4.z * bf2f(g2[2 * e2])     + w4.w * bf2f(g3[2 * e2]);
            float v1 = w4.x * bf2f(g0[2 * e2 + 1]) + w4.y * bf2f(g1[2 * e2 + 1])
                     + w4.z * bf2f(g2[2 * e2 + 1]) + w4.w * bf2f(g3[2 * e2 + 1]);
            bw[e2] = pk2bf(v0, v1);
        }
        *(u32x4*)&Bs[0][bpx][wchunk] = bw;
    }
    __syncthreads();

    for (int p = 0; p < 108; ++p) {
        int tap = p / 12, cs = p - tap * 12;
        int buf = p & 1;
        // ---- issue gathers for phase p+1 (latency hides under MFMA) ----
        s16x8 g0, g1, g2, g3;
        float4 w4n;
        bool have = (p + 1 < 108);
        if (have) {
            int pn = p + 1;
            int ntap = pn / 12, ncs = pn - ntap * 12;
            w4n = meta_w[ntap * 64 + bpx];
            int4 i4 = meta_i[ntap * 64 + bpx];
            const char* base = xb + ncs * 128 + oct * 16;
            g0 = *(const s16x8*)(base + i4.x);
            g1 = *(const s16x8*)(base + i4.y);
            g2 = *(const s16x8*)(base + i4.z);
            g3 = *(const s16x8*)(base + i4.w);
        }
        // ---- MFMA phase p: 2 K-steps over buf ----
#pragma unroll
        for (int kk = 0; kk < 2; ++kk) {
            int s = tap * 24 + cs * 2 + kk;
            const s16x8* ap = (const s16x8*)(A + ((size_t)(s * 48 + afrag0) * 64 + lane) * 8);
            s16x8 a0 = ap[0];
            s16x8 a1 = ap[64];
            s16x8 a2 = ap[128];
            int rchunk = ((kk * 4 + q) ^ (lane & 7)) * 8;   // swizzled read chunk
            const ushort_t* brow = &Bs[buf][wn * 32 + (lane & 15)][rchunk];
            s16x8 b0 = *(const s16x8*)brow;
            s16x8 b1 = *(const s16x8*)(brow + 16 * 72);
            acc[0][0] = __builtin_amdgcn_mfma_f32_16x16x32_bf16(a0, b0, acc[0][0], 0, 0, 0);
            acc[0][1] = __builtin_amdgcn_mfma_f32_16x16x32_bf16(a0, b1, acc[0][1], 0, 0, 0);
            acc[1][0] = __builtin_amdgcn_mfma_f32_16x16x32_bf16(a1, b0, acc[1][0], 0, 0, 0);
            acc[1][1] = __builtin_amdgcn_mfma_f32_16x16x32_bf16(a1, b1, acc[1][1], 0, 0, 0);
            acc[2][0] = __builtin_amdgcn_mfma_f32_16x16x32_bf16(a2, b0, acc[2][0], 0, 0, 0);
            acc[2][1] = __builtin_amdgcn_mfma_f32_16x16x32_bf16(a2, b1, acc[2][1], 0, 0, 0);
        }
        // ---- build phase p+1 into buf^1 ----
        if (have) {
            u32x4 bw;
#pragma unroll
            for (int e2 = 0; e2 < 4; ++e2) {
                float v0 = w4n.x * bf2f(g0[2 * e2])     + w4n.y * bf2f(g1[2 * e2])
                         + w4n.z * bf2f(g2[2 * e2])     + w4n.w * bf2f(g3[2 * e2]);
                float v1 = w4n.x * bf2f(g0[2 * e2 + 1]) + w4n.y * bf2f(g1[2 * e2 + 1])
                         + w4n.z * bf2f(g2[2 * e2 + 1]) + w4n.w * bf2f(g3[2 * e2 + 1]);
                bw[e2] = pk2bf(v0, v1);
            }
            *(u32x4*)&Bs[buf ^ 1][bpx][wchunk] = bw;
        }
        __syncthreads();
    }

    // ---- epilogue (no bias: per-channel bias cancels in batch-norm) ----
    int pxo = p0 + wn * 32 + (lane & 15);
    int obase = otile * 192 + wm * 48;
#pragma unroll
    for (int f = 0; f < 3; ++f) {
        int orow = obase + f * 16 + ((lane >> 4) << 2);
#pragma unroll
        for (int r = 0; r < 4; ++r) {
            size_t rowoff = ((size_t)(b * 768 + orow + r) << 10);
            y[rowoff + pxo]      = acc[f][0][r];
            y[rowoff + pxo + 16] = acc[f][1][r];
        }
    }
}

// ---------------------------------------------------------------------------
__global__ __launch_bounds__(256) void stats_kernel(
    const float* __restrict__ y, float* __restrict__ stats)
{
    int o = blockIdx.x;
    int tid = threadIdx.x;
    float s1 = 0.f, s2 = 0.f;
    for (int i = tid; i < B_N * HW; i += 256) {
        int b = i >> 10, hw = i & 1023;
        float v = y[(((size_t)b * 768 + o) << 10) + hw];
        s1 += v; s2 += v * v;
    }
#pragma unroll
    for (int off = 32; off > 0; off >>= 1) {
        s1 += __shfl_down(s1, off);
        s2 += __shfl_down(s2, off);
    }
    __shared__ float ls1[4], ls2[4];
    int wid = tid >> 6, lane = tid & 63;
    if (lane == 0) { ls1[wid] = s1; ls2[wid] = s2; }
    __syncthreads();
    if (tid == 0) {
        float t1 = ls1[0] + ls1[1] + ls1[2] + ls1[3];
        float t2 = ls2[0] + ls2[1] + ls2[2] + ls2[3];
        float mean = t1 * (1.0f / 8192.0f);
        float var  = t2 * (1.0f / 8192.0f) - mean * mean;
        stats[o]       = mean;
        stats[768 + o] = 1.0f / sqrtf(var + 1e-5f);
    }
}

__global__ __launch_bounds__(256) void finalize_kernel(
    const float* __restrict__ x, const float* __restrict__ stats,
    const float* __restrict__ gamma, const float* __restrict__ beta,
    float* __restrict__ y)
{
    const int total4 = B_N * 768 * HW / 4;
    for (int f = blockIdx.x * 256 + threadIdx.x; f < total4;
         f += gridDim.x * 256) {
        int e = f << 2;
        int o = (e >> 10) % 768;
        float mean = stats[o], rstd = stats[768 + o];
        float ga = gamma[o], be = beta[o];
        float4 v  = ((const float4*)y)[f];
        float4 xv = ((const float4*)x)[f];
        float4 r;
        {
            float yn = (v.x - mean) * rstd * ga + be;
            r.x = xv.x + 0.5f * yn * (1.0f + erff(yn * 0.70710678f));
        }
        {
            float yn = (v.y - mean) * rstd * ga + be;
            r.y = xv.y + 0.5f * yn * (1.0f + erff(yn * 0.70710678f));
        }
        {
            float yn = (v.z - mean) * rstd * ga + be;
            r.z = xv.z + 0.5f * yn * (1.0f + erff(yn * 0.70710678f));
        }
        {
            float yn = (v.w - mean) * rstd * ga + be;
            r.w = xv.w + 0.5f * yn * (1.0f + erff(yn * 0.70710678f));
        }
        ((float4*)y)[f] = r;
    }
}

// ---------------------------------------------------------------------------
extern "C" void kernel_launch(void* const* d_in, const int* in_sizes, int n_in,
                              void* d_out, int out_size, void* d_ws, size_t ws_size,
                              hipStream_t stream)
{
    const float* x        = (const float*)d_in[0];
    const float* proj_w   = (const float*)d_in[1];
    const float* offset_w = (const float*)d_in[3];
    const float* offset_b = (const float*)d_in[4];
    const float* mask_w   = (const float*)d_in[5];
    const float* mask_b   = (const float*)d_in[6];
    const float* gamma    = (const float*)d_in[7];
    const float* beta     = (const float*)d_in[8];

    char* ws = (char*)d_ws;
    float*    offs  = (float*)(ws);                  //   589824 B
    float*    maskb = (float*)(ws + 589824);         //   294912 B
    float*    stats = (float*)(ws + 884736);         //     6144 B
    ushort_t* A     = (ushort_t*)(ws + 890880);      // 10616832 B
    ushort_t* A2    = (ushort_t*)(ws + 11507712);    //   442368 B
    ushort_t* xt    = (ushort_t*)(ws + 11950080);    // 12582912 B  (tot ~24.5MB)
    float* y = (float*)d_out;

    prepack_xt<<<1536, 256, 0, stream>>>(x, xt);
    prepack_om<<<108, 256, 0, stream>>>(offset_w, mask_w, A2);
    prepack_proj<<<2592, 256, 0, stream>>>(proj_w, A);
    offmask_mfma<<<256, 256, 0, stream>>>(xt, A2, offset_b, mask_b, offs, maskb);
    deform_mfma<<<512, 512, 0, stream>>>(xt, A, offs, maskb, y);
    stats_kernel<<<768, 256, 0, stream>>>(y, stats);
    finalize_kernel<<<2048, 256, 0, stream>>>(x, stats, gamma, beta, y);
}

// Round 5
// 270.594 us; speedup vs baseline: 12.1967x; 1.0597x over previous
//
#include <hip/hip_runtime.h>
#include <math.h>

typedef __attribute__((ext_vector_type(4))) float f32x4;
typedef __attribute__((ext_vector_type(8))) short s16x8;
typedef __attribute__((ext_vector_type(4))) unsigned int u32x4;
typedef unsigned short ushort_t;

#define HW   1024
#define C_IN 768
#define B_N  8

__device__ inline ushort_t f2bf(float f) {
    unsigned u = __builtin_bit_cast(unsigned, f);
    unsigned r = u + 0x7FFFu + ((u >> 16) & 1u);
    return (ushort_t)(r >> 16);
}
__device__ inline float bf2f(short s) {
    return __builtin_bit_cast(float, ((unsigned)(ushort_t)s) << 16);
}

// ---------------------------------------------------------------------------
// x [b][c][pos] fp32  ->  xt [b][pos][c] bf16   (row = 768 ch = 1536 B)
// ---------------------------------------------------------------------------
__global__ __launch_bounds__(256) void prepack_xt(
    const float* __restrict__ x, ushort_t* __restrict__ xt)
{
    __shared__ ushort_t tile[64][66];
    int bid = blockIdx.x;                 // 8 * 12 * 16
    int b  = bid / 192;
    int r  = bid % 192;
    int cg = r / 16, pg = r % 16;
    int c0 = cg * 64, p0 = pg * 64;
    int t = threadIdx.x;
#pragma unroll
    for (int i = 0; i < 16; ++i) {
        int idx = t + i * 256;
        int cr = idx >> 6, col = idx & 63;
        tile[cr][col] = f2bf(x[(((size_t)b * C_IN + c0 + cr) << 10) + p0 + col]);
    }
    __syncthreads();
#pragma unroll
    for (int i = 0; i < 16; ++i) {
        int idx = t + i * 256;
        int pr = idx >> 6, col = idx & 63;
        xt[((size_t)(b << 10) + p0 + pr) * C_IN + c0 + col] = tile[col][pr];
    }
}

// ---------------------------------------------------------------------------
// proj_w -> MFMA A-frag layout, k = tap*768 + c (tap-major).
// ---------------------------------------------------------------------------
__global__ __launch_bounds__(256) void prepack_proj(
    const float* __restrict__ pw, ushort_t* __restrict__ A)
{
    int t = blockIdx.x * 256 + threadIdx.x;     // 216*48*64 threads
    int lane = t & 63;
    int smi  = t >> 6;
    int s  = smi / 48, mf = smi - s * 48;
    int o  = mf * 16 + (lane & 15);
    int k0 = s * 32 + ((lane >> 4) << 3);
    int tap = k0 / 768;
    int c   = k0 - tap * 768;
    const float* src = pw + (size_t)o * 6912 + (size_t)c * 9 + tap;
    s16x8 pk;
#pragma unroll
    for (int e = 0; e < 8; ++e) pk[e] = (short)f2bf(src[e * 9]);
    *(s16x8*)(A + (size_t)smi * 512 + lane * 8) = pk;
}

__global__ __launch_bounds__(256) void prepack_om(
    const float* __restrict__ offw, const float* __restrict__ mskw,
    ushort_t* __restrict__ A2)
{
    int t = blockIdx.x * 256 + threadIdx.x;     // 216*2*64 threads
    int lane = t & 63;
    int smi  = t >> 6;
    int s  = smi >> 1, mf = smi & 1;
    int oc = mf * 16 + (lane & 15);
    int k0 = s * 32 + ((lane >> 4) << 3);
    int tap = k0 / 768;
    int c   = k0 - tap * 768;
    s16x8 pk;
#pragma unroll
    for (int e = 0; e < 8; ++e) pk[e] = 0;
    if (oc < 27) {
        const float* src = (oc < 18)
            ? offw + ((size_t)oc        * 768 + c) * 9 + tap
            : mskw + ((size_t)(oc - 18) * 768 + c) * 9 + tap;
#pragma unroll
        for (int e = 0; e < 8; ++e) pk[e] = (short)f2bf(src[e * 9]);
    }
    *(s16x8*)(A2 + (size_t)smi * 512 + lane * 8) = pk;
}

// ---------------------------------------------------------------------------
// Offset/mask conv: LDS-free MFMA GEMM. B-frags are 16B contiguous in xt.
// ---------------------------------------------------------------------------
__global__ __launch_bounds__(256) void offmask_mfma(
    const ushort_t* __restrict__ xt, const ushort_t* __restrict__ A2,
    const float* __restrict__ offb, const float* __restrict__ mbias,
    float* __restrict__ offs, float* __restrict__ maskb)
{
    int bid = blockIdx.x;               // b*32 + pt
    int b = bid >> 5, pt = bid & 31;
    int p0 = pt << 5;
    int t = threadIdx.x, lane = t & 63, wv = t >> 6;
    int mf = wv >> 1, nf = wv & 1;
    int q = lane >> 4;
    int px = p0 + nf * 16 + (lane & 15);
    int h = px >> 5, w = px & 31;
    const char* xb = (const char*)xt + (size_t)b * (HW * 1536);
    f32x4 acc = (f32x4){0.f, 0.f, 0.f, 0.f};

    for (int tap = 0; tap < 9; ++tap) {
        int yy = h + tap / 3 - 1, xx = w + tap % 3 - 1;
        bool ok = (yy >= 0 && yy < 32 && xx >= 0 && xx < 32);
        int pos = ok ? (yy * 32 + xx) : 0;
        const char* bp = xb + (size_t)pos * 1536 + q * 16;
        for (int cs = 0; cs < 24; ++cs) {
            int s = tap * 24 + cs;
            s16x8 bf;
            if (ok) bf = *(const s16x8*)(bp + cs * 64);
            else    bf = (s16x8){0, 0, 0, 0, 0, 0, 0, 0};
            s16x8 af = *(const s16x8*)(A2 + ((size_t)(s * 2 + mf) * 64 + lane) * 8);
            acc = __builtin_amdgcn_mfma_f32_16x16x32_bf16(af, bf, acc, 0, 0, 0);
        }
    }
#pragma unroll
    for (int r = 0; r < 4; ++r) {
        int oc = mf * 16 + ((lane >> 4) << 2) + r;
        if (oc < 18) {
            float v = acc[r] + offb[oc];
            v = fminf(fmaxf(v, -8.f), 8.f);        // max_off = 32//4
            offs[((b * 18 + oc) << 10) + px] = v;
        } else if (oc < 27) {
            float v = acc[r] + mbias[oc - 18];
            maskb[((b * 9 + oc - 18) << 10) + px] = 2.f / (1.f + expf(-v));
        }
    }
}

// ---------------------------------------------------------------------------
// Deformable conv GEMM, tile 192(o) x 64(px), 8 waves (4 wm x 2 wn).
// 108 phases of 64 channels x 1 tap. Depth-2 gather prefetch (issue at p for
// p+2), weak barriers (lgkmcnt(0)+s_barrier: vmcnt stays in flight across
// phases), Bs rows exactly 128B so the XOR chunk swizzle is 2-way (free).
// ---------------------------------------------------------------------------
__global__ __launch_bounds__(512, 4) void deform_mfma(
    const ushort_t* __restrict__ xt, const ushort_t* __restrict__ Amat,
    const float* __restrict__ offs, const float* __restrict__ maskb,
    float* __restrict__ y)
{
    __shared__ float4 meta_w[576];
    __shared__ int4   meta_i[576];
    __shared__ __align__(16) ushort_t Bs[2][64][64];   // 128B rows, XOR swizzle

    int id = blockIdx.x;                  // b = id&7 == XCD -> xt slab L2-local
    int b = id & 7;
    int pxt = (id >> 3) & 15;
    int otile = id >> 7;
    int p0 = pxt << 6;
    int t = threadIdx.x, lane = t & 63, wv = t >> 6;
    int wm = wv >> 1, wn = wv & 1;
    int q4 = lane >> 4;

    // build-phase lane map: 8 lanes = 64-ch span of ONE pixel-neighbor
    int bpx = wv * 8 + (lane >> 3);       // 0..63 pixel
    int oct = lane & 7;                   // 0..7 channel-octet (16B)
    const int wchunk = (oct ^ (bpx & 7)) * 8;

    // ---- bilinear metadata (64 px x 9 taps), byte offsets into xt rows ----
    for (int i = t; i < 576; i += 512) {
        int k = i >> 6, j = i & 63;
        int hw = p0 + j, h = hw >> 5, w = hw & 31;
        float dy = offs[((b * 18 + 2 * k) << 10) + hw];
        float dx = offs[((b * 18 + 2 * k + 1) << 10) + hw];
        float m  = maskb[((b * 9 + k) << 10) + hw];
        float ys = dy + (float)(h + k / 3 - 1);
        float xs = dx + (float)(w + k % 3 - 1);
        float fy = floorf(ys), fx = floorf(xs);
        float wy = ys - fy, wx = xs - fx;
        int iy0 = (int)fy, ix0 = (int)fx;
        int iy1 = iy0 + 1, ix1 = ix0 + 1;
        float vy0 = (iy0 >= 0 && iy0 < 32) ? 1.f : 0.f;
        float vy1 = (iy1 >= 0 && iy1 < 32) ? 1.f : 0.f;
        float vx0 = (ix0 >= 0 && ix0 < 32) ? 1.f : 0.f;
        float vx1 = (ix1 >= 0 && ix1 < 32) ? 1.f : 0.f;
        int cy0 = min(max(iy0, 0), 31), cx0 = min(max(ix0, 0), 31);
        int cy1 = min(max(iy1, 0), 31), cx1 = min(max(ix1, 0), 31);
        float4 wv4;
        wv4.x = (1.f - wy) * (1.f - wx) * m * vy0 * vx0;
        wv4.y = (1.f - wy) * wx         * m * vy0 * vx1;
        wv4.z = wy         * (1.f - wx) * m * vy1 * vx0;
        wv4.w = wy         * wx         * m * vy1 * vx1;
        meta_w[i] = wv4;
        meta_i[i] = make_int4((cy0 * 32 + cx0) * 1536, (cy0 * 32 + cx1) * 1536,
                              (cy1 * 32 + cx0) * 1536, (cy1 * 32 + cx1) * 1536);
    }
    asm volatile("s_waitcnt lgkmcnt(0)" ::: "memory");
    __builtin_amdgcn_s_barrier();

    f32x4 acc[3][2];
#pragma unroll
    for (int f = 0; f < 3; ++f)
#pragma unroll
        for (int n = 0; n < 2; ++n) acc[f][n] = (f32x4){0.f, 0.f, 0.f, 0.f};

    const char* xb = (const char*)xt + (size_t)b * (HW * 1536);
    const int afrag0 = otile * 12 + wm * 3;

    s16x8 ga0, ga1, ga2, ga3, gb0, gb1, gb2, gb3;
    float4 w4a, w4b;

#define WBAR() do { asm volatile("s_waitcnt lgkmcnt(0)" ::: "memory"); \
                    __builtin_amdgcn_s_barrier(); } while (0)

#define ISSUE(G0, G1, G2, G3, W4, qq) do {                                  \
    int nt_ = (qq) / 12, nc_ = (qq) - nt_ * 12;                             \
    W4 = meta_w[nt_ * 64 + bpx];                                            \
    int4 i4_ = meta_i[nt_ * 64 + bpx];                                      \
    const char* bsrc_ = xb + nc_ * 128 + oct * 16;                          \
    G0 = *(const s16x8*)(bsrc_ + i4_.x);                                    \
    G1 = *(const s16x8*)(bsrc_ + i4_.y);                                    \
    G2 = *(const s16x8*)(bsrc_ + i4_.z);                                    \
    G3 = *(const s16x8*)(bsrc_ + i4_.w);                                    \
} while (0)

#define BUILD(G0, G1, G2, G3, W4, BUF) do {                                 \
    u32x4 bw_;                                                              \
    _Pragma("unroll")                                                       \
    for (int e2 = 0; e2 < 4; ++e2) {                                        \
        float v0_ = W4.x * bf2f(G0[2*e2])   + W4.y * bf2f(G1[2*e2])         \
                  + W4.z * bf2f(G2[2*e2])   + W4.w * bf2f(G3[2*e2]);        \
        float v1_ = W4.x * bf2f(G0[2*e2+1]) + W4.y * bf2f(G1[2*e2+1])       \
                  + W4.z * bf2f(G2[2*e2+1]) + W4.w * bf2f(G3[2*e2+1]);      \
        unsigned rr_;                                                       \
        asm("v_cvt_pk_bf16_f32 %0, %1, %2" : "=v"(rr_) : "v"(v0_), "v"(v1_)); \
        bw_[e2] = rr_;                                                      \
    }                                                                       \
    *(u32x4*)&Bs[BUF][bpx][wchunk] = bw_;                                   \
} while (0)

#define MFMA_PHASE(P, BUF) do {                                             \
    _Pragma("unroll")                                                       \
    for (int kk = 0; kk < 2; ++kk) {                                        \
        int s_ = 2 * (P) + kk;                                              \
        const s16x8* ap_ = (const s16x8*)(Amat +                            \
            ((size_t)(s_ * 48 + afrag0) * 64 + lane) * 8);                  \
        s16x8 a0_ = ap_[0], a1_ = ap_[64], a2_ = ap_[128];                  \
        int rc_ = ((kk * 4 + q4) ^ (lane & 7)) * 8;                         \
        s16x8 b0_ = *(const s16x8*)&Bs[BUF][wn * 32 + (lane & 15)][rc_];    \
        s16x8 b1_ = *(const s16x8*)&Bs[BUF][wn * 32 + 16 + (lane & 15)][rc_]; \
        acc[0][0] = __builtin_amdgcn_mfma_f32_16x16x32_bf16(a0_, b0_, acc[0][0], 0, 0, 0); \
        acc[0][1] = __builtin_amdgcn_mfma_f32_16x16x32_bf16(a0_, b1_, acc[0][1], 0, 0, 0); \
        acc[1][0] = __builtin_amdgcn_mfma_f32_16x16x32_bf16(a1_, b0_, acc[1][0], 0, 0, 0); \
        acc[1][1] = __builtin_amdgcn_mfma_f32_16x16x32_bf16(a1_, b1_, acc[1][1], 0, 0, 0); \
        acc[2][0] = __builtin_amdgcn_mfma_f32_16x16x32_bf16(a2_, b0_, acc[2][0], 0, 0, 0); \
        acc[2][1] = __builtin_amdgcn_mfma_f32_16x16x32_bf16(a2_, b1_, acc[2][1], 0, 0, 0); \
    }                                                                       \
} while (0)

    // ---- prologue: gathers for phases 0 and 1; build phase 0 ----
    ISSUE(ga0, ga1, ga2, ga3, w4a, 0);
    ISSUE(gb0, gb1, gb2, gb3, w4b, 1);
    BUILD(ga0, ga1, ga2, ga3, w4a, 0);
    WBAR();

    // ---- main loop, unrolled by 2: even phases use set a, odd use set b ----
    for (int pp = 0; pp < 54; ++pp) {
        int pe = 2 * pp;
        if (pp < 53) ISSUE(ga0, ga1, ga2, ga3, w4a, pe + 2);
        MFMA_PHASE(pe, 0);
        BUILD(gb0, gb1, gb2, gb3, w4b, 1);      // phase pe+1 (always exists)
        WBAR();

        int po = pe + 1;
        if (pp < 53) ISSUE(gb0, gb1, gb2, gb3, w4b, po + 2);
        MFMA_PHASE(po, 1);
        if (pp < 53) BUILD(ga0, ga1, ga2, ga3, w4a, 0);   // phase po+1
        WBAR();
    }

    // ---- epilogue (no bias: per-channel bias cancels in batch-norm) ----
    int pxo = p0 + wn * 32 + (lane & 15);
    int obase = otile * 192 + wm * 48;
#pragma unroll
    for (int f = 0; f < 3; ++f) {
        int orow = obase + f * 16 + ((lane >> 4) << 2);
#pragma unroll
        for (int r = 0; r < 4; ++r) {
            size_t rowoff = ((size_t)(b * 768 + orow + r) << 10);
            y[rowoff + pxo]      = acc[f][0][r];
            y[rowoff + pxo + 16] = acc[f][1][r];
        }
    }
#undef WBAR
#undef ISSUE
#undef BUILD
#undef MFMA_PHASE
}

// ---------------------------------------------------------------------------
__global__ __launch_bounds__(256) void stats_kernel(
    const float* __restrict__ y, float* __restrict__ stats)
{
    int o = blockIdx.x;
    int tid = threadIdx.x;
    float s1 = 0.f, s2 = 0.f;
    for (int i = tid; i < B_N * HW; i += 256) {
        int b = i >> 10, hw = i & 1023;
        float v = y[(((size_t)b * 768 + o) << 10) + hw];
        s1 += v; s2 += v * v;
    }
#pragma unroll
    for (int off = 32; off > 0; off >>= 1) {
        s1 += __shfl_down(s1, off);
        s2 += __shfl_down(s2, off);
    }
    __shared__ float ls1[4], ls2[4];
    int wid = tid >> 6, lane = tid & 63;
    if (lane == 0) { ls1[wid] = s1; ls2[wid] = s2; }
    __syncthreads();
    if (tid == 0) {
        float t1 = ls1[0] + ls1[1] + ls1[2] + ls1[3];
        float t2 = ls2[0] + ls2[1] + ls2[2] + ls2[3];
        float mean = t1 * (1.0f / 8192.0f);
        float var  = t2 * (1.0f / 8192.0f) - mean * mean;
        stats[o]       = mean;
        stats[768 + o] = 1.0f / sqrtf(var + 1e-5f);
    }
}

__global__ __launch_bounds__(256) void finalize_kernel(
    const float* __restrict__ x, const float* __restrict__ stats,
    const float* __restrict__ gamma, const float* __restrict__ beta,
    float* __restrict__ y)
{
    const int total4 = B_N * 768 * HW / 4;
    for (int f = blockIdx.x * 256 + threadIdx.x; f < total4;
         f += gridDim.x * 256) {
        int e = f << 2;
        int o = (e >> 10) % 768;
        float mean = stats[o], rstd = stats[768 + o];
        float ga = gamma[o], be = beta[o];
        float4 v  = ((const float4*)y)[f];
        float4 xv = ((const float4*)x)[f];
        float4 r;
        {
            float yn = (v.x - mean) * rstd * ga + be;
            r.x = xv.x + 0.5f * yn * (1.0f + erff(yn * 0.70710678f));
        }
        {
            float yn = (v.y - mean) * rstd * ga + be;
            r.y = xv.y + 0.5f * yn * (1.0f + erff(yn * 0.70710678f));
        }
        {
            float yn = (v.z - mean) * rstd * ga + be;
            r.z = xv.z + 0.5f * yn * (1.0f + erff(yn * 0.70710678f));
        }
        {
            float yn = (v.w - mean) * rstd * ga + be;
            r.w = xv.w + 0.5f * yn * (1.0f + erff(yn * 0.70710678f));
        }
        ((float4*)y)[f] = r;
    }
}

// ---------------------------------------------------------------------------
extern "C" void kernel_launch(void* const* d_in, const int* in_sizes, int n_in,
                              void* d_out, int out_size, void* d_ws, size_t ws_size,
                              hipStream_t stream)
{
    const float* x        = (const float*)d_in[0];
    const float* proj_w   = (const float*)d_in[1];
    const float* offset_w = (const float*)d_in[3];
    const float* offset_b = (const float*)d_in[4];
    const float* mask_w   = (const float*)d_in[5];
    const float* mask_b   = (const float*)d_in[6];
    const float* gamma    = (const float*)d_in[7];
    const float* beta     = (const float*)d_in[8];

    char* ws = (char*)d_ws;
    float*    offs  = (float*)(ws);                  //   589824 B
    float*    maskb = (float*)(ws + 589824);         //   294912 B
    float*    stats = (float*)(ws + 884736);         //     6144 B
    ushort_t* A     = (ushort_t*)(ws + 890880);      // 10616832 B
    ushort_t* A2    = (ushort_t*)(ws + 11507712);    //   442368 B
    ushort_t* xt    = (ushort_t*)(ws + 11950080);    // 12582912 B  (tot ~24.5MB)
    float* y = (float*)d_out;

    prepack_xt<<<1536, 256, 0, stream>>>(x, xt);
    prepack_om<<<108, 256, 0, stream>>>(offset_w, mask_w, A2);
    prepack_proj<<<2592, 256, 0, stream>>>(proj_w, A);
    offmask_mfma<<<256, 256, 0, stream>>>(xt, A2, offset_b, mask_b, offs, maskb);
    deform_mfma<<<512, 512, 0, stream>>>(xt, A, offs, maskb, y);
    stats_kernel<<<768, 256, 0, stream>>>(y, stats);
    finalize_kernel<<<2048, 256, 0, stream>>>(x, stats, gamma, beta, y);
}